// Round 7
// baseline (420.166 us; speedup 1.0000x reference)
//
#include <hip/hip_runtime.h>
#include <hip/hip_bf16.h>
#include <math.h>

#define NN 50000
#define NE 600000
#define NF 256
#define NHID 128
#define HEADS 8
#define D0 16
#define NCLS 64
#define NB1 196  // (NN+255)/256

#define PK0 (9 * 8 * 64 * 8)   // Bp0: 8 col-tiles of W0 + 1 alpha tile (W0A)
#define PK1 (4 * 32 * 64 * 8)  // Bp1

typedef __attribute__((ext_vector_type(8))) short short8;
typedef __attribute__((ext_vector_type(4))) float floatx4;

__device__ __forceinline__ float bf16lo(uint v) { return __uint_as_float((v & 0xffffu) << 16); }
__device__ __forceinline__ float bf16hi(uint v) { return __uint_as_float(v & 0xffff0000u); }
__device__ __forceinline__ uint packbf16(float a, float b) {
    return (uint)__bfloat16_as_ushort(__float2bfloat16(a)) |
           ((uint)__bfloat16_as_ushort(__float2bfloat16(b)) << 16);
}
__device__ __forceinline__ short f2bf(float v) {
    return (short)__bfloat16_as_ushort(__float2bfloat16(v));
}

// ---------------- CSR build ----------------

__global__ void deg_kernel(const int* __restrict__ ei, int* __restrict__ deg) {
    int e = blockIdx.x * 256 + threadIdx.x;
    if (e < NE) atomicAdd(&deg[ei[NE + e]], 1);
}

__global__ void scan1_kernel(const int* __restrict__ deg, int* __restrict__ rs,
                             int* __restrict__ bsum) {
    __shared__ int sh[256];
    int tid = threadIdx.x;
    int i = blockIdx.x * 256 + tid;
    int v = (i < NN) ? deg[i] : 0;
    sh[tid] = v;
    __syncthreads();
    for (int off = 1; off < 256; off <<= 1) {
        int t = (tid >= off) ? sh[tid - off] : 0;
        __syncthreads();
        sh[tid] += t;
        __syncthreads();
    }
    if (i < NN) rs[i] = sh[tid] - v;  // exclusive
    if (tid == 255) bsum[blockIdx.x] = sh[255];
}

__global__ void scan2_kernel(const int* __restrict__ bsum, int* __restrict__ bsumx) {
    __shared__ int sh[256];
    int tid = threadIdx.x;
    int v = (tid < NB1) ? bsum[tid] : 0;
    sh[tid] = v;
    __syncthreads();
    for (int off = 1; off < 256; off <<= 1) {
        int t = (tid >= off) ? sh[tid - off] : 0;
        __syncthreads();
        sh[tid] += t;
        __syncthreads();
    }
    if (tid < NB1) bsumx[tid] = sh[tid] - v;
}

__global__ void scan3_kernel(int* __restrict__ rs, const int* __restrict__ bsumx) {
    int i = blockIdx.x * 256 + threadIdx.x;
    if (i < NN) rs[i] += bsumx[i >> 8];
}

__global__ void scatter_kernel(const int* __restrict__ ei, const int* __restrict__ rs,
                               int* __restrict__ cnt2, int* __restrict__ csr) {
    int e = blockIdx.x * 256 + threadIdx.x;
    if (e >= NE) return;
    int s = ei[e], d = ei[NE + e];
    int pos = rs[d] + atomicAdd(&cnt2[d], 1);
    csr[pos] = s;
}

// ---------------- cast & merged weight-prep ----------------

__global__ void cast_bf16_kernel(const float* __restrict__ in, short* __restrict__ o, int n4) {
    int i = blockIdx.x * 256 + threadIdx.x;
    if (i >= n4) return;
    float4 v = ((const float4*)in)[i];
    short4 r;
    r.x = f2bf(v.x); r.y = f2bf(v.y); r.z = f2bf(v.z); r.w = f2bf(v.w);
    ((short4*)o)[i] = r;
}

// One kernel: Bp0 (9 tiles: 8 = W0 cols, tile 8 = W0@[As|Ad]); Bp1; wS/wD.
__global__ void prep_kernel(const float* __restrict__ W0, const float* __restrict__ aS0,
                            const float* __restrict__ aD0, const float* __restrict__ W1,
                            const float* __restrict__ aS1, const float* __restrict__ aD1,
                            short* __restrict__ Bp0, short* __restrict__ Bp1,
                            float* __restrict__ wS, float* __restrict__ wD) {
    int tid = blockIdx.x * 256 + threadIdx.x;
    if (tid < PK0) {
        int j = tid & 7, l = (tid >> 3) & 63, ks = (tid >> 9) & 7, t = tid >> 12;
        int k = ks * 32 + (l >> 4) * 8 + j;
        float v;
        if (t < 8) {
            int c = t * 16 + (l & 15);
            v = W0[(size_t)k * 128 + c];
        } else {  // alpha tile: col jj<8 -> as0 head jj; jj>=8 -> ad0 head jj-8
            int jj = l & 15;
            int hh = jj & 7;
            const float* av = (jj < 8) ? aS0 : aD0;
            float sum = 0.f;
            for (int dd = 0; dd < D0; ++dd)
                sum += W0[(size_t)k * 128 + hh * D0 + dd] * av[hh * D0 + dd];
            v = sum;
        }
        Bp0[tid] = f2bf(v);
    } else if (tid < PK0 + PK1) {
        int t2 = tid - PK0;
        int j = t2 & 7, l = (t2 >> 3) & 63, ks = (t2 >> 9) & 31, t = t2 >> 14;
        int kk = ks * 32 + (l >> 4) * 8 + j;
        int c = t * 16 + (l & 15);
        Bp1[t2] = f2bf(W1[(size_t)(kk & 127) * 512 + (kk >> 7) * 64 + c] * 0.125f);
    } else if (tid < PK0 + PK1 + HEADS * NHID) {
        int t3 = tid - PK0 - PK1;
        int h = t3 >> 7, k = t3 & 127;
        float sS = 0.f, sD = 0.f;
        for (int d2 = 0; d2 < NCLS; ++d2) {
            float w = W1[(size_t)k * 512 + h * NCLS + d2];
            sS += w * aS1[h * NCLS + d2];
            sD += w * aD1[h * NCLS + d2];
        }
        wS[t3] = sS;
        wD[t3] = sD;
    }
}

// ---------------- MFMA GEMMs ----------------

// h0b = xb @ W0 (bf16 out) AND as0/ad0 = xb @ W0A (alpha tile), fused.
__global__ __launch_bounds__(256) void gemm0_mfma(const short* __restrict__ xb,
                                                  const short* __restrict__ Bp,
                                                  ushort* __restrict__ h0b,
                                                  float* __restrict__ as0,
                                                  float* __restrict__ ad0) {
    int lane = threadIdx.x & 63, wave = threadIdx.x >> 6;
    int rg = wave >> 1, cg = wave & 1;
    int q = lane >> 4, c16 = lane & 15;
    int row0 = blockIdx.x * 32 + rg * 16;
    int arow = row0 + c16;
    if (arow > NN - 1) arow = NN - 1;
    const short* ap = xb + (size_t)arow * NF + q * 8;
    floatx4 acc[5] = {};
#pragma unroll
    for (int ks = 0; ks < 8; ++ks) {
        short8 af = *(const short8*)(ap + ks * 32);
#pragma unroll
        for (int tt = 0; tt < 4; ++tt) {
            int t = cg * 4 + tt;
            short8 bf = *(const short8*)(Bp + (((size_t)t * 8 + ks) * 64 + lane) * 8);
            acc[tt] = __builtin_amdgcn_mfma_f32_16x16x32_bf16(af, bf, acc[tt], 0, 0, 0);
        }
        if (cg) {  // wave-uniform: alpha tile t=8
            short8 bf = *(const short8*)(Bp + (((size_t)8 * 8 + ks) * 64 + lane) * 8);
            acc[4] = __builtin_amdgcn_mfma_f32_16x16x32_bf16(af, bf, acc[4], 0, 0, 0);
        }
    }
#pragma unroll
    for (int r = 0; r < 4; ++r) {
        int grow = row0 + q * 4 + r;
        if (grow >= NN) continue;
#pragma unroll
        for (int tt = 0; tt < 4; ++tt)
            h0b[(size_t)grow * NHID + cg * 64 + tt * 16 + c16] =
                (ushort)f2bf(acc[tt][r]);
        if (cg) {
            float v = acc[4][r];
            if (c16 < 8) as0[grow * 8 + c16] = v;
            else         ad0[grow * 8 + (c16 - 8)] = v;
        }
    }
}

// out = log_softmax( AGG @ Bp1 + b1 )
__global__ __launch_bounds__(256) void gemm1_mfma(const short* __restrict__ AGG,
                                                  const short* __restrict__ Bp,
                                                  const float* __restrict__ b1,
                                                  float* __restrict__ out) {
    int lane = threadIdx.x & 63, wave = threadIdx.x >> 6;
    int q = lane >> 4, c16 = lane & 15;
    int row0 = blockIdx.x * 64 + wave * 16;
    int arow = row0 + c16;
    if (arow > NN - 1) arow = NN - 1;
    const short* ap = AGG + (size_t)arow * 1024 + q * 8;
    floatx4 acc[4] = {};
    for (int ks = 0; ks < 32; ++ks) {
        short8 af = *(const short8*)(ap + ks * 32);
#pragma unroll
        for (int t = 0; t < 4; ++t) {
            short8 bf = *(const short8*)(Bp + (((size_t)t * 32 + ks) * 64 + lane) * 8);
            acc[t] = __builtin_amdgcn_mfma_f32_16x16x32_bf16(af, bf, acc[t], 0, 0, 0);
        }
    }
    float bias[4];
#pragma unroll
    for (int t = 0; t < 4; ++t) bias[t] = b1[t * 16 + c16];
#pragma unroll
    for (int r = 0; r < 4; ++r) {
        int grow = row0 + q * 4 + r;
        float z[4];
        float mx = -INFINITY;
#pragma unroll
        for (int t = 0; t < 4; ++t) {
            z[t] = acc[t][r] + bias[t];
            mx = fmaxf(mx, z[t]);
        }
        mx = fmaxf(mx, __shfl_xor(mx, 1));
        mx = fmaxf(mx, __shfl_xor(mx, 2));
        mx = fmaxf(mx, __shfl_xor(mx, 4));
        mx = fmaxf(mx, __shfl_xor(mx, 8));
        float s = 0.f;
#pragma unroll
        for (int t = 0; t < 4; ++t) s += expf(z[t] - mx);
        s += __shfl_xor(s, 1);
        s += __shfl_xor(s, 2);
        s += __shfl_xor(s, 4);
        s += __shfl_xor(s, 8);
        float lse = mx + logf(s);
        if (grow < NN) {
#pragma unroll
            for (int t = 0; t < 4; ++t)
                out[(size_t)grow * NCLS + t * 16 + c16] = z[t] - lse;
        }
    }
}

// as1[n,h] = x1[n,:] . wS[h,:]   (x1 in bf16, uint4-vectorized)
__global__ void alpha1_kernel(const ushort* __restrict__ x1b, const float* __restrict__ wS,
                              const float* __restrict__ wD, float* __restrict__ as_out,
                              float* __restrict__ ad_out) {
    int idx = blockIdx.x * 256 + threadIdx.x;
    if (idx >= NN * HEADS) return;
    int n = idx >> 3, h = idx & 7;
    const uint4* xp = (const uint4*)(x1b + (size_t)n * NHID);
    const float* sp = wS + h * NHID;
    const float* dp = wD + h * NHID;
    float s = 0.f, d = 0.f;
#pragma unroll
    for (int c = 0; c < 16; ++c) {
        uint4 v = xp[c];
        float f[8] = {bf16lo(v.x), bf16hi(v.x), bf16lo(v.y), bf16hi(v.y),
                      bf16lo(v.z), bf16hi(v.z), bf16lo(v.w), bf16hi(v.w)};
#pragma unroll
        for (int j = 0; j < 8; ++j) {
            s += f[j] * sp[c * 8 + j];
            d += f[j] * dp[c * 8 + j];
        }
    }
    as_out[idx] = s;
    ad_out[idx] = d;
}

// ---------------- fused edge kernels (one wave per dst, single pass) ----------------
// softmax WITHOUT max subtraction (shift-invariant; logits are O(+-6) here).
// Full 8-edge chunks: compile-time unroll with all 8 gathers hoisted (in flight);
// tail (<8 edges): runtime loop (no dummy work).

__global__ __launch_bounds__(256) void fused_edge0(
    const int* __restrict__ rs, const int* __restrict__ deg, const int* __restrict__ csr,
    const ushort* __restrict__ h0b, const float* __restrict__ as0, const float* __restrict__ ad0,
    const float* __restrict__ b0, ushort* __restrict__ x1b) {
    int d = (blockIdx.x * 256 + threadIdx.x) >> 6;
    int lane = threadIdx.x & 63;
    if (d >= NN) return;
    int row = rs[d], dg = deg[d];
    int hl = lane & 7, g = lane >> 3;
    int hp = lane >> 3;  // head owning this lane's dim pair (2*lane, 2*lane+1)
    float adv = ad0[d * 8 + hl];
    float den = 0.f, acc0 = 0.f, acc1 = 0.f;
    int base = 0;
    for (; base + 8 <= dg; base += 8) {
        int s = csr[row + base + g];
        float ev = as0[s * 8 + hl] + adv;
        ev = ev > 0.f ? ev : 0.2f * ev;
        float p = __expf(ev);
        den += p;
        uint v[8];
#pragma unroll
        for (int g2 = 0; g2 < 8; ++g2) {
            int sg = __shfl(s, g2 * 8);
            v[g2] = *(const uint*)(h0b + (size_t)sg * NHID + 2 * lane);
        }
#pragma unroll
        for (int g2 = 0; g2 < 8; ++g2) {
            float ph = __shfl(p, g2 * 8 + hp);
            acc0 += bf16lo(v[g2]) * ph;
            acc1 += bf16hi(v[g2]) * ph;
        }
    }
    int rem = dg - base;
    if (rem) {
        int s = (g < rem) ? csr[row + base + g] : 0;
        float ev = as0[s * 8 + hl] + adv;
        ev = ev > 0.f ? ev : 0.2f * ev;
        float p = (g < rem) ? __expf(ev) : 0.f;
        den += p;
        for (int g2 = 0; g2 < rem; ++g2) {
            int sg = __shfl(s, g2 * 8);
            float ph = __shfl(p, g2 * 8 + hp);
            uint v = *(const uint*)(h0b + (size_t)sg * NHID + 2 * lane);
            acc0 += bf16lo(v) * ph;
            acc1 += bf16hi(v) * ph;
        }
    }
    den += __shfl_xor(den, 8);
    den += __shfl_xor(den, 16);
    den += __shfl_xor(den, 32);
    float dh = __shfl(den, hp);
    float inv = 1.f / (dh + 1e-16f);
    float2 bb = ((const float2*)b0)[lane];
    float o0 = acc0 * inv + bb.x;
    float o1 = acc1 * inv + bb.y;
    o0 = o0 > 0.f ? o0 : expf(o0) - 1.f;
    o1 = o1 > 0.f ? o1 : expf(o1) - 1.f;
    *(uint*)(x1b + (size_t)d * NHID + 2 * lane) = packbf16(o0, o1);
}

__global__ __launch_bounds__(256) void fused_edge1(
    const int* __restrict__ rs, const int* __restrict__ deg, const int* __restrict__ csr,
    const ushort* __restrict__ x1b, const float* __restrict__ as1, const float* __restrict__ ad1,
    ushort* __restrict__ AGG) {
    int d = (blockIdx.x * 256 + threadIdx.x) >> 6;
    int lane = threadIdx.x & 63;
    if (d >= NN) return;
    int row = rs[d], dg = deg[d];
    int hl = lane & 7, g = lane >> 3;
    float adv = ad1[d * 8 + hl];
    float den = 0.f;
    float acc[HEADS][2] = {};
    int base = 0;
    for (; base + 8 <= dg; base += 8) {
        int s = csr[row + base + g];
        float ev = as1[s * 8 + hl] + adv;
        ev = ev > 0.f ? ev : 0.2f * ev;
        float p = __expf(ev);
        den += p;
        uint v[8];
#pragma unroll
        for (int g2 = 0; g2 < 8; ++g2) {
            int sg = __shfl(s, g2 * 8);
            v[g2] = *(const uint*)(x1b + (size_t)sg * NHID + 2 * lane);
        }
#pragma unroll
        for (int g2 = 0; g2 < 8; ++g2) {
            float lo = bf16lo(v[g2]), hi = bf16hi(v[g2]);
#pragma unroll
            for (int h = 0; h < HEADS; ++h) {
                float ph = __shfl(p, g2 * 8 + h);
                acc[h][0] += lo * ph;
                acc[h][1] += hi * ph;
            }
        }
    }
    int rem = dg - base;
    if (rem) {
        int s = (g < rem) ? csr[row + base + g] : 0;
        float ev = as1[s * 8 + hl] + adv;
        ev = ev > 0.f ? ev : 0.2f * ev;
        float p = (g < rem) ? __expf(ev) : 0.f;
        den += p;
        for (int g2 = 0; g2 < rem; ++g2) {
            int sg = __shfl(s, g2 * 8);
            uint v = *(const uint*)(x1b + (size_t)sg * NHID + 2 * lane);
            float lo = bf16lo(v), hi = bf16hi(v);
#pragma unroll
            for (int h = 0; h < HEADS; ++h) {
                float ph = __shfl(p, g2 * 8 + h);
                acc[h][0] += lo * ph;
                acc[h][1] += hi * ph;
            }
        }
    }
    den += __shfl_xor(den, 8);
    den += __shfl_xor(den, 16);
    den += __shfl_xor(den, 32);
#pragma unroll
    for (int h = 0; h < HEADS; ++h) {
        float dh = __shfl(den, h);
        float inv = 1.f / (dh + 1e-16f);
        *(uint*)(AGG + (size_t)d * 1024 + h * NHID + 2 * lane) =
            packbf16(acc[h][0] * inv, acc[h][1] * inv);
    }
}

// ---------------- launch ----------------

extern "C" void kernel_launch(void* const* d_in, const int* in_sizes, int n_in,
                              void* d_out, int out_size, void* d_ws, size_t ws_size,
                              hipStream_t stream) {
    const float* x   = (const float*)d_in[0];
    const int*   ei  = (const int*)d_in[1];
    const float* W0  = (const float*)d_in[2];
    const float* aS0 = (const float*)d_in[3];
    const float* aD0 = (const float*)d_in[4];
    const float* b0  = (const float*)d_in[5];
    const float* W1  = (const float*)d_in[6];
    const float* aS1 = (const float*)d_in[7];
    const float* aD1 = (const float*)d_in[8];
    const float* b1  = (const float*)d_in[9];
    float* out = (float*)d_out;

    char* ws = (char*)d_ws;
    ushort* x1b = (ushort*)ws; ws += (size_t)NN * NHID * 2;           // 12.8 MB
    ushort* h0b = (ushort*)ws; ws += (size_t)NN * NHID * 2;           // 12.8 MB
    ushort* AGG = (ushort*)ws; ws += (size_t)NN * 1024 * 2;           // 102.4 MB
    short* xb   = (short*)ws; ws += (size_t)NN * NF * 2;              // 25.6 MB
    float* as0  = (float*)ws; ws += (size_t)NN * HEADS * 4;
    float* ad0  = (float*)ws; ws += (size_t)NN * HEADS * 4;
    float* as1  = (float*)ws; ws += (size_t)NN * HEADS * 4;
    float* ad1  = (float*)ws; ws += (size_t)NN * HEADS * 4;
    short* Bp0  = (short*)ws; ws += (size_t)PK0 * 2;
    short* Bp1  = (short*)ws; ws += (size_t)PK1 * 2;
    float* wS   = (float*)ws; ws += (size_t)HEADS * NHID * 4;
    float* wD   = (float*)ws; ws += (size_t)HEADS * NHID * 4;
    int* deg    = (int*)ws; ws += (size_t)NN * 4;
    int* cnt2   = (int*)ws; ws += (size_t)NN * 4;                     // adjacent to deg
    int* rs     = (int*)ws; ws += (size_t)NN * 4;
    int* bsum   = (int*)ws; ws += 256 * 4;
    int* bsumx  = (int*)ws; ws += 256 * 4;
    int* csr    = (int*)ws; ws += (size_t)NE * 4;                     // 2.4 MB

    const int NH = NN * HEADS;
    const int PREPN = PK0 + PK1 + HEADS * NHID;

    // ---- CSR build (shared by both layers) ----
    hipMemsetAsync(deg, 0, (size_t)2 * NN * 4, stream);  // deg + cnt2
    deg_kernel<<<(NE + 255) / 256, 256, 0, stream>>>(ei, deg);
    scan1_kernel<<<NB1, 256, 0, stream>>>(deg, rs, bsum);
    scan2_kernel<<<1, 256, 0, stream>>>(bsum, bsumx);
    scan3_kernel<<<NB1, 256, 0, stream>>>(rs, bsumx);
    scatter_kernel<<<(NE + 255) / 256, 256, 0, stream>>>(ei, rs, cnt2, csr);

    // ---- weight prep (both layers, one kernel) ----
    cast_bf16_kernel<<<(NN * NF / 4 + 255) / 256, 256, 0, stream>>>(x, xb, NN * NF / 4);
    prep_kernel<<<(PREPN + 255) / 256, 256, 0, stream>>>(W0, aS0, aD0, W1, aS1, aD1,
                                                         Bp0, Bp1, wS, wD);

    // ---- layer 0 ----
    gemm0_mfma<<<(NN + 31) / 32, 256, 0, stream>>>(xb, Bp0, h0b, as0, ad0);
    fused_edge0<<<(NN + 3) / 4, 256, 0, stream>>>(rs, deg, csr, h0b, as0, ad0, b0, x1b);

    // ---- layer 1 ----
    alpha1_kernel<<<(NH + 255) / 256, 256, 0, stream>>>(x1b, wS, wD, as1, ad1);
    fused_edge1<<<(NN + 3) / 4, 256, 0, stream>>>(rs, deg, csr, x1b, as1, ad1, AGG);
    gemm1_mfma<<<(NN + 63) / 64, 256, 0, stream>>>((const short*)AGG, Bp1, b1, out);
}

// Round 8
// 411.933 us; speedup vs baseline: 1.0200x; 1.0200x over previous
//
#include <hip/hip_runtime.h>
#include <hip/hip_bf16.h>
#include <math.h>

#define NN 50000
#define NE 600000
#define NF 256
#define NHID 128
#define HEADS 8
#define D0 16
#define NCLS 64
#define NB1 196  // (NN+255)/256

#define PK0 (9 * 8 * 64 * 8)   // Bp0: 8 col-tiles of W0 + 1 alpha tile (W0A)
#define PK1 (4 * 32 * 64 * 8)  // Bp1

typedef __attribute__((ext_vector_type(8))) short short8;
typedef __attribute__((ext_vector_type(4))) float floatx4;

__device__ __forceinline__ float bf16lo(uint v) { return __uint_as_float((v & 0xffffu) << 16); }
__device__ __forceinline__ float bf16hi(uint v) { return __uint_as_float(v & 0xffff0000u); }
__device__ __forceinline__ uint packbf16(float a, float b) {
    return (uint)__bfloat16_as_ushort(__float2bfloat16(a)) |
           ((uint)__bfloat16_as_ushort(__float2bfloat16(b)) << 16);
}
__device__ __forceinline__ short f2bf(float v) {
    return (short)__bfloat16_as_ushort(__float2bfloat16(v));
}

// ---------------- CSR build ----------------

__global__ void deg_kernel(const int* __restrict__ ei, int* __restrict__ deg) {
    int e = blockIdx.x * 256 + threadIdx.x;
    if (e < NE) atomicAdd(&deg[ei[NE + e]], 1);
}

__global__ void scan1_kernel(const int* __restrict__ deg, int* __restrict__ rs,
                             int* __restrict__ bsum) {
    __shared__ int sh[256];
    int tid = threadIdx.x;
    int i = blockIdx.x * 256 + tid;
    int v = (i < NN) ? deg[i] : 0;
    sh[tid] = v;
    __syncthreads();
    for (int off = 1; off < 256; off <<= 1) {
        int t = (tid >= off) ? sh[tid - off] : 0;
        __syncthreads();
        sh[tid] += t;
        __syncthreads();
    }
    if (i < NN) rs[i] = sh[tid] - v;  // exclusive
    if (tid == 255) bsum[blockIdx.x] = sh[255];
}

__global__ void scan2_kernel(const int* __restrict__ bsum, int* __restrict__ bsumx) {
    __shared__ int sh[256];
    int tid = threadIdx.x;
    int v = (tid < NB1) ? bsum[tid] : 0;
    sh[tid] = v;
    __syncthreads();
    for (int off = 1; off < 256; off <<= 1) {
        int t = (tid >= off) ? sh[tid - off] : 0;
        __syncthreads();
        sh[tid] += t;
        __syncthreads();
    }
    if (tid < NB1) bsumx[tid] = sh[tid] - v;
}

__global__ void scan3_kernel(int* __restrict__ rs, const int* __restrict__ bsumx) {
    int i = blockIdx.x * 256 + threadIdx.x;
    if (i < NN) rs[i] += bsumx[i >> 8];
}

__global__ void scatter_kernel(const int* __restrict__ ei, const int* __restrict__ rs,
                               int* __restrict__ cnt2, int* __restrict__ csr) {
    int e = blockIdx.x * 256 + threadIdx.x;
    if (e >= NE) return;
    int s = ei[e], d = ei[NE + e];
    int pos = rs[d] + atomicAdd(&cnt2[d], 1);
    csr[pos] = s;
}

// ---------------- cast & merged weight-prep ----------------

__global__ void cast_bf16_kernel(const float* __restrict__ in, short* __restrict__ o, int n4) {
    int i = blockIdx.x * 256 + threadIdx.x;
    if (i >= n4) return;
    float4 v = ((const float4*)in)[i];
    short4 r;
    r.x = f2bf(v.x); r.y = f2bf(v.y); r.z = f2bf(v.z); r.w = f2bf(v.w);
    ((short4*)o)[i] = r;
}

// One kernel: Bp0 (9 tiles: 8 = W0 cols, tile 8 = W0@[As|Ad]); Bp1; wS/wD.
__global__ void prep_kernel(const float* __restrict__ W0, const float* __restrict__ aS0,
                            const float* __restrict__ aD0, const float* __restrict__ W1,
                            const float* __restrict__ aS1, const float* __restrict__ aD1,
                            short* __restrict__ Bp0, short* __restrict__ Bp1,
                            float* __restrict__ wS, float* __restrict__ wD) {
    int tid = blockIdx.x * 256 + threadIdx.x;
    if (tid < PK0) {
        int j = tid & 7, l = (tid >> 3) & 63, ks = (tid >> 9) & 7, t = tid >> 12;
        int k = ks * 32 + (l >> 4) * 8 + j;
        float v;
        if (t < 8) {
            int c = t * 16 + (l & 15);
            v = W0[(size_t)k * 128 + c];
        } else {  // alpha tile: col jj<8 -> as0 head jj; jj>=8 -> ad0 head jj-8
            int jj = l & 15;
            int hh = jj & 7;
            const float* av = (jj < 8) ? aS0 : aD0;
            float sum = 0.f;
            for (int dd = 0; dd < D0; ++dd)
                sum += W0[(size_t)k * 128 + hh * D0 + dd] * av[hh * D0 + dd];
            v = sum;
        }
        Bp0[tid] = f2bf(v);
    } else if (tid < PK0 + PK1) {
        int t2 = tid - PK0;
        int j = t2 & 7, l = (t2 >> 3) & 63, ks = (t2 >> 9) & 31, t = t2 >> 14;
        int kk = ks * 32 + (l >> 4) * 8 + j;
        int c = t * 16 + (l & 15);
        Bp1[t2] = f2bf(W1[(size_t)(kk & 127) * 512 + (kk >> 7) * 64 + c] * 0.125f);
    } else if (tid < PK0 + PK1 + HEADS * NHID) {
        int t3 = tid - PK0 - PK1;
        int h = t3 >> 7, k = t3 & 127;
        float sS = 0.f, sD = 0.f;
        for (int d2 = 0; d2 < NCLS; ++d2) {
            float w = W1[(size_t)k * 512 + h * NCLS + d2];
            sS += w * aS1[h * NCLS + d2];
            sD += w * aD1[h * NCLS + d2];
        }
        wS[t3] = sS;
        wD[t3] = sD;
    }
}

// ---------------- MFMA GEMMs ----------------

// h0b = xb @ W0 (bf16 out) AND as0/ad0 = xb @ W0A (alpha tile), fused.
__global__ __launch_bounds__(256) void gemm0_mfma(const short* __restrict__ xb,
                                                  const short* __restrict__ Bp,
                                                  ushort* __restrict__ h0b,
                                                  float* __restrict__ as0,
                                                  float* __restrict__ ad0) {
    int lane = threadIdx.x & 63, wave = threadIdx.x >> 6;
    int rg = wave >> 1, cg = wave & 1;
    int q = lane >> 4, c16 = lane & 15;
    int row0 = blockIdx.x * 32 + rg * 16;
    int arow = row0 + c16;
    if (arow > NN - 1) arow = NN - 1;
    const short* ap = xb + (size_t)arow * NF + q * 8;
    floatx4 acc[5] = {};
#pragma unroll
    for (int ks = 0; ks < 8; ++ks) {
        short8 af = *(const short8*)(ap + ks * 32);
#pragma unroll
        for (int tt = 0; tt < 4; ++tt) {
            int t = cg * 4 + tt;
            short8 bf = *(const short8*)(Bp + (((size_t)t * 8 + ks) * 64 + lane) * 8);
            acc[tt] = __builtin_amdgcn_mfma_f32_16x16x32_bf16(af, bf, acc[tt], 0, 0, 0);
        }
        if (cg) {  // wave-uniform: alpha tile t=8
            short8 bf = *(const short8*)(Bp + (((size_t)8 * 8 + ks) * 64 + lane) * 8);
            acc[4] = __builtin_amdgcn_mfma_f32_16x16x32_bf16(af, bf, acc[4], 0, 0, 0);
        }
    }
#pragma unroll
    for (int r = 0; r < 4; ++r) {
        int grow = row0 + q * 4 + r;
        if (grow >= NN) continue;
#pragma unroll
        for (int tt = 0; tt < 4; ++tt)
            h0b[(size_t)grow * NHID + cg * 64 + tt * 16 + c16] =
                (ushort)f2bf(acc[tt][r]);
        if (cg) {
            float v = acc[4][r];
            if (c16 < 8) as0[grow * 8 + c16] = v;
            else         ad0[grow * 8 + (c16 - 8)] = v;
        }
    }
}

// out = log_softmax( AGG @ Bp1 + b1 )
__global__ __launch_bounds__(256) void gemm1_mfma(const short* __restrict__ AGG,
                                                  const short* __restrict__ Bp,
                                                  const float* __restrict__ b1,
                                                  float* __restrict__ out) {
    int lane = threadIdx.x & 63, wave = threadIdx.x >> 6;
    int q = lane >> 4, c16 = lane & 15;
    int row0 = blockIdx.x * 64 + wave * 16;
    int arow = row0 + c16;
    if (arow > NN - 1) arow = NN - 1;
    const short* ap = AGG + (size_t)arow * 1024 + q * 8;
    floatx4 acc[4] = {};
    for (int ks = 0; ks < 32; ++ks) {
        short8 af = *(const short8*)(ap + ks * 32);
#pragma unroll
        for (int t = 0; t < 4; ++t) {
            short8 bf = *(const short8*)(Bp + (((size_t)t * 32 + ks) * 64 + lane) * 8);
            acc[t] = __builtin_amdgcn_mfma_f32_16x16x32_bf16(af, bf, acc[t], 0, 0, 0);
        }
    }
    float bias[4];
#pragma unroll
    for (int t = 0; t < 4; ++t) bias[t] = b1[t * 16 + c16];
#pragma unroll
    for (int r = 0; r < 4; ++r) {
        int grow = row0 + q * 4 + r;
        float z[4];
        float mx = -INFINITY;
#pragma unroll
        for (int t = 0; t < 4; ++t) {
            z[t] = acc[t][r] + bias[t];
            mx = fmaxf(mx, z[t]);
        }
        mx = fmaxf(mx, __shfl_xor(mx, 1));
        mx = fmaxf(mx, __shfl_xor(mx, 2));
        mx = fmaxf(mx, __shfl_xor(mx, 4));
        mx = fmaxf(mx, __shfl_xor(mx, 8));
        float s = 0.f;
#pragma unroll
        for (int t = 0; t < 4; ++t) s += expf(z[t] - mx);
        s += __shfl_xor(s, 1);
        s += __shfl_xor(s, 2);
        s += __shfl_xor(s, 4);
        s += __shfl_xor(s, 8);
        float lse = mx + logf(s);
        if (grow < NN) {
#pragma unroll
            for (int t = 0; t < 4; ++t)
                out[(size_t)grow * NCLS + t * 16 + c16] = z[t] - lse;
        }
    }
}

// as1[n,h] = x1[n,:] . wS[h,:]   (x1 in bf16, uint4-vectorized)
__global__ void alpha1_kernel(const ushort* __restrict__ x1b, const float* __restrict__ wS,
                              const float* __restrict__ wD, float* __restrict__ as_out,
                              float* __restrict__ ad_out) {
    int idx = blockIdx.x * 256 + threadIdx.x;
    if (idx >= NN * HEADS) return;
    int n = idx >> 3, h = idx & 7;
    const uint4* xp = (const uint4*)(x1b + (size_t)n * NHID);
    const float* sp = wS + h * NHID;
    const float* dp = wD + h * NHID;
    float s = 0.f, d = 0.f;
#pragma unroll
    for (int c = 0; c < 16; ++c) {
        uint4 v = xp[c];
        float f[8] = {bf16lo(v.x), bf16hi(v.x), bf16lo(v.y), bf16hi(v.y),
                      bf16lo(v.z), bf16hi(v.z), bf16lo(v.w), bf16hi(v.w)};
#pragma unroll
        for (int j = 0; j < 8; ++j) {
            s += f[j] * sp[c * 8 + j];
            d += f[j] * dp[c * 8 + j];
        }
    }
    as_out[idx] = s;
    ad_out[idx] = d;
}

// ---------------- fused edge kernels (one wave per dst, single pass) ----------------
// Round-4 structure: runtime inner loop, minimal VGPR (TLP > ILP for this
// latency-bound gather). float2 accumulators for packed FMA.
// softmax WITHOUT max subtraction (shift-invariant; logits are O(+-6) here).

__global__ __launch_bounds__(256) void fused_edge0(
    const int* __restrict__ rs, const int* __restrict__ deg, const int* __restrict__ csr,
    const ushort* __restrict__ h0b, const float* __restrict__ as0, const float* __restrict__ ad0,
    const float* __restrict__ b0, ushort* __restrict__ x1b) {
    int d = (blockIdx.x * 256 + threadIdx.x) >> 6;
    int lane = threadIdx.x & 63;
    if (d >= NN) return;
    int row = rs[d], dg = deg[d];
    int hl = lane & 7, g = lane >> 3;
    int hp = lane >> 3;  // head owning this lane's dim pair (2*lane, 2*lane+1)
    float adv = ad0[d * 8 + hl];
    float den = 0.f;
    float2 acc = {0.f, 0.f};
    for (int base = 0; base < dg; base += 8) {
        int i = base + g;
        int s = (i < dg) ? csr[row + i] : 0;
        float ev = as0[s * 8 + hl] + adv;
        ev = ev > 0.f ? ev : 0.2f * ev;
        float p = (i < dg) ? __expf(ev) : 0.f;
        den += p;
        int nv = dg - base;
        if (nv > 8) nv = 8;
        for (int g2 = 0; g2 < nv; ++g2) {
            int sg = __shfl(s, g2 * 8);
            float ph = __shfl(p, g2 * 8 + hp);
            uint v = *(const uint*)(h0b + (size_t)sg * NHID + 2 * lane);
            acc.x += bf16lo(v) * ph;
            acc.y += bf16hi(v) * ph;
        }
    }
    den += __shfl_xor(den, 8);
    den += __shfl_xor(den, 16);
    den += __shfl_xor(den, 32);
    float dh = __shfl(den, hp);
    float inv = 1.f / (dh + 1e-16f);
    float2 bb = ((const float2*)b0)[lane];
    float o0 = acc.x * inv + bb.x;
    float o1 = acc.y * inv + bb.y;
    o0 = o0 > 0.f ? o0 : expf(o0) - 1.f;
    o1 = o1 > 0.f ? o1 : expf(o1) - 1.f;
    *(uint*)(x1b + (size_t)d * NHID + 2 * lane) = packbf16(o0, o1);
}

__global__ __launch_bounds__(256) void fused_edge1(
    const int* __restrict__ rs, const int* __restrict__ deg, const int* __restrict__ csr,
    const ushort* __restrict__ x1b, const float* __restrict__ as1, const float* __restrict__ ad1,
    ushort* __restrict__ AGG) {
    int d = (blockIdx.x * 256 + threadIdx.x) >> 6;
    int lane = threadIdx.x & 63;
    if (d >= NN) return;
    int row = rs[d], dg = deg[d];
    int hl = lane & 7, g = lane >> 3;
    float adv = ad1[d * 8 + hl];
    float den = 0.f;
    float2 acc[HEADS] = {};
    for (int base = 0; base < dg; base += 8) {
        int i = base + g;
        int s = (i < dg) ? csr[row + i] : 0;
        float ev = as1[s * 8 + hl] + adv;
        ev = ev > 0.f ? ev : 0.2f * ev;
        float p = (i < dg) ? __expf(ev) : 0.f;
        den += p;
        int nv = dg - base;
        if (nv > 8) nv = 8;
        for (int g2 = 0; g2 < nv; ++g2) {
            int sg = __shfl(s, g2 * 8);
            uint v = *(const uint*)(x1b + (size_t)sg * NHID + 2 * lane);
            float2 xv = {bf16lo(v), bf16hi(v)};
#pragma unroll
            for (int h = 0; h < HEADS; ++h) {
                float ph = __shfl(p, g2 * 8 + h);
                acc[h].x += xv.x * ph;
                acc[h].y += xv.y * ph;
            }
        }
    }
    den += __shfl_xor(den, 8);
    den += __shfl_xor(den, 16);
    den += __shfl_xor(den, 32);
#pragma unroll
    for (int h = 0; h < HEADS; ++h) {
        float dh = __shfl(den, h);
        float inv = 1.f / (dh + 1e-16f);
        *(uint*)(AGG + (size_t)d * 1024 + h * NHID + 2 * lane) =
            packbf16(acc[h].x * inv, acc[h].y * inv);
    }
}

// ---------------- launch ----------------

extern "C" void kernel_launch(void* const* d_in, const int* in_sizes, int n_in,
                              void* d_out, int out_size, void* d_ws, size_t ws_size,
                              hipStream_t stream) {
    const float* x   = (const float*)d_in[0];
    const int*   ei  = (const int*)d_in[1];
    const float* W0  = (const float*)d_in[2];
    const float* aS0 = (const float*)d_in[3];
    const float* aD0 = (const float*)d_in[4];
    const float* b0  = (const float*)d_in[5];
    const float* W1  = (const float*)d_in[6];
    const float* aS1 = (const float*)d_in[7];
    const float* aD1 = (const float*)d_in[8];
    const float* b1  = (const float*)d_in[9];
    float* out = (float*)d_out;

    char* ws = (char*)d_ws;
    ushort* x1b = (ushort*)ws; ws += (size_t)NN * NHID * 2;           // 12.8 MB
    ushort* h0b = (ushort*)ws; ws += (size_t)NN * NHID * 2;           // 12.8 MB
    ushort* AGG = (ushort*)ws; ws += (size_t)NN * 1024 * 2;           // 102.4 MB
    short* xb   = (short*)ws; ws += (size_t)NN * NF * 2;              // 25.6 MB
    float* as0  = (float*)ws; ws += (size_t)NN * HEADS * 4;
    float* ad0  = (float*)ws; ws += (size_t)NN * HEADS * 4;
    float* as1  = (float*)ws; ws += (size_t)NN * HEADS * 4;
    float* ad1  = (float*)ws; ws += (size_t)NN * HEADS * 4;
    short* Bp0  = (short*)ws; ws += (size_t)PK0 * 2;
    short* Bp1  = (short*)ws; ws += (size_t)PK1 * 2;
    float* wS   = (float*)ws; ws += (size_t)HEADS * NHID * 4;
    float* wD   = (float*)ws; ws += (size_t)HEADS * NHID * 4;
    int* deg    = (int*)ws; ws += (size_t)NN * 4;
    int* cnt2   = (int*)ws; ws += (size_t)NN * 4;                     // adjacent to deg
    int* rs     = (int*)ws; ws += (size_t)NN * 4;
    int* bsum   = (int*)ws; ws += 256 * 4;
    int* bsumx  = (int*)ws; ws += 256 * 4;
    int* csr    = (int*)ws; ws += (size_t)NE * 4;                     // 2.4 MB

    const int NH = NN * HEADS;
    const int PREPN = PK0 + PK1 + HEADS * NHID;

    // ---- CSR build (shared by both layers) ----
    hipMemsetAsync(deg, 0, (size_t)2 * NN * 4, stream);  // deg + cnt2
    deg_kernel<<<(NE + 255) / 256, 256, 0, stream>>>(ei, deg);
    scan1_kernel<<<NB1, 256, 0, stream>>>(deg, rs, bsum);
    scan2_kernel<<<1, 256, 0, stream>>>(bsum, bsumx);
    scan3_kernel<<<NB1, 256, 0, stream>>>(rs, bsumx);
    scatter_kernel<<<(NE + 255) / 256, 256, 0, stream>>>(ei, rs, cnt2, csr);

    // ---- weight prep (both layers, one kernel) ----
    cast_bf16_kernel<<<(NN * NF / 4 + 255) / 256, 256, 0, stream>>>(x, xb, NN * NF / 4);
    prep_kernel<<<(PREPN + 255) / 256, 256, 0, stream>>>(W0, aS0, aD0, W1, aS1, aD1,
                                                         Bp0, Bp1, wS, wD);

    // ---- layer 0 ----
    gemm0_mfma<<<(NN + 31) / 32, 256, 0, stream>>>(xb, Bp0, h0b, as0, ad0);
    fused_edge0<<<(NN + 3) / 4, 256, 0, stream>>>(rs, deg, csr, h0b, as0, ad0, b0, x1b);

    // ---- layer 1 ----
    alpha1_kernel<<<(NH + 255) / 256, 256, 0, stream>>>(x1b, wS, wD, as1, ad1);
    fused_edge1<<<(NN + 3) / 4, 256, 0, stream>>>(rs, deg, csr, x1b, as1, ad1, AGG);
    gemm1_mfma<<<(NN + 63) / 64, 256, 0, stream>>>((const short*)AGG, Bp1, b1, out);
}

// Round 9
// 404.814 us; speedup vs baseline: 1.0379x; 1.0176x over previous
//
#include <hip/hip_runtime.h>
#include <hip/hip_bf16.h>
#include <math.h>

#define NN 50000
#define NE 600000
#define NF 256
#define NHID 128
#define HEADS 8
#define D0 16
#define NCLS 64
#define NB1 196  // (NN+255)/256

#define PK0 (9 * 8 * 64 * 8)   // Bp0: 8 col-tiles of W0 + 1 alpha tile (W0A)
#define PK1 (4 * 32 * 64 * 8)  // Bp1
#define CASTN (NN * NF / 4)    // 3.2M float4 groups
#define PREPN (PK0 + PK1 + HEADS * NHID)

typedef __attribute__((ext_vector_type(8))) short short8;
typedef __attribute__((ext_vector_type(4))) float floatx4;

__device__ __forceinline__ float bf16lo(uint v) { return __uint_as_float((v & 0xffffu) << 16); }
__device__ __forceinline__ float bf16hi(uint v) { return __uint_as_float(v & 0xffff0000u); }
__device__ __forceinline__ uint packbf16(float a, float b) {
    return (uint)__bfloat16_as_ushort(__float2bfloat16(a)) |
           ((uint)__bfloat16_as_ushort(__float2bfloat16(b)) << 16);
}
__device__ __forceinline__ short f2bf(float v) {
    return (short)__bfloat16_as_ushort(__float2bfloat16(v));
}

// ---------------- CSR scan/scatter ----------------

__global__ void scan1_kernel(const int* __restrict__ deg, int* __restrict__ rs,
                             int* __restrict__ bsum) {
    __shared__ int sh[256];
    int tid = threadIdx.x;
    int i = blockIdx.x * 256 + tid;
    int v = (i < NN) ? deg[i] : 0;
    sh[tid] = v;
    __syncthreads();
    for (int off = 1; off < 256; off <<= 1) {
        int t = (tid >= off) ? sh[tid - off] : 0;
        __syncthreads();
        sh[tid] += t;
        __syncthreads();
    }
    if (i < NN) rs[i] = sh[tid] - v;  // exclusive
    if (tid == 255) bsum[blockIdx.x] = sh[255];
}

__global__ void scan2_kernel(const int* __restrict__ bsum, int* __restrict__ bsumx) {
    __shared__ int sh[256];
    int tid = threadIdx.x;
    int v = (tid < NB1) ? bsum[tid] : 0;
    sh[tid] = v;
    __syncthreads();
    for (int off = 1; off < 256; off <<= 1) {
        int t = (tid >= off) ? sh[tid - off] : 0;
        __syncthreads();
        sh[tid] += t;
        __syncthreads();
    }
    if (tid < NB1) bsumx[tid] = sh[tid] - v;
}

__global__ void scan3_kernel(int* __restrict__ rs, const int* __restrict__ bsumx) {
    int i = blockIdx.x * 256 + threadIdx.x;
    if (i < NN) rs[i] += bsumx[i >> 8];
}

__global__ void scatter_kernel(const int* __restrict__ ei, const int* __restrict__ rs,
                               int* __restrict__ cnt2, int* __restrict__ csr) {
    int e = blockIdx.x * 256 + threadIdx.x;
    if (e >= NE) return;
    int s = ei[e], d = ei[NE + e];
    int pos = rs[d] + atomicAdd(&cnt2[d], 1);
    csr[pos] = s;
}

// ---------------- fused cast + degree + weight-prep (independent streams) ----------------

__global__ void fused_prep_kernel(const float* __restrict__ x, short* __restrict__ xb,
                                  const int* __restrict__ ei, int* __restrict__ deg,
                                  const float* __restrict__ W0, const float* __restrict__ aS0,
                                  const float* __restrict__ aD0, const float* __restrict__ W1,
                                  const float* __restrict__ aS1, const float* __restrict__ aD1,
                                  short* __restrict__ Bp0, short* __restrict__ Bp1,
                                  float* __restrict__ wS, float* __restrict__ wD) {
    int i = blockIdx.x * 256 + threadIdx.x;
    if (i < CASTN) {
        float4 v = ((const float4*)x)[i];
        short4 r;
        r.x = f2bf(v.x); r.y = f2bf(v.y); r.z = f2bf(v.z); r.w = f2bf(v.w);
        ((short4*)xb)[i] = r;
        return;
    }
    int e = i - CASTN;
    if (e < NE) {
        atomicAdd(&deg[ei[NE + e]], 1);
        return;
    }
    int tid = e - NE;
    if (tid < PK0) {
        int j = tid & 7, l = (tid >> 3) & 63, ks = (tid >> 9) & 7, t = tid >> 12;
        int k = ks * 32 + (l >> 4) * 8 + j;
        float v;
        if (t < 8) {
            int c = t * 16 + (l & 15);
            v = W0[(size_t)k * 128 + c];
        } else {  // alpha tile: col jj<8 -> as0 head jj; jj>=8 -> ad0 head jj-8
            int jj = l & 15;
            int hh = jj & 7;
            const float* av = (jj < 8) ? aS0 : aD0;
            float sum = 0.f;
            for (int dd = 0; dd < D0; ++dd)
                sum += W0[(size_t)k * 128 + hh * D0 + dd] * av[hh * D0 + dd];
            v = sum;
        }
        Bp0[tid] = f2bf(v);
    } else if (tid < PK0 + PK1) {
        int t2 = tid - PK0;
        int j = t2 & 7, l = (t2 >> 3) & 63, ks = (t2 >> 9) & 31, t = t2 >> 14;
        int kk = ks * 32 + (l >> 4) * 8 + j;
        int c = t * 16 + (l & 15);
        Bp1[t2] = f2bf(W1[(size_t)(kk & 127) * 512 + (kk >> 7) * 64 + c] * 0.125f);
    } else if (tid < PREPN) {
        int t3 = tid - PK0 - PK1;
        int h = t3 >> 7, k = t3 & 127;
        float sS = 0.f, sD = 0.f;
        for (int d2 = 0; d2 < NCLS; ++d2) {
            float w = W1[(size_t)k * 512 + h * NCLS + d2];
            sS += w * aS1[h * NCLS + d2];
            sD += w * aD1[h * NCLS + d2];
        }
        wS[t3] = sS;
        wD[t3] = sD;
    }
}

// ---------------- MFMA GEMMs ----------------

// h0b = xb @ W0 (bf16 out) AND as0/ad0 = xb @ W0A (alpha tile), fused.
__global__ __launch_bounds__(256) void gemm0_mfma(const short* __restrict__ xb,
                                                  const short* __restrict__ Bp,
                                                  ushort* __restrict__ h0b,
                                                  float* __restrict__ as0,
                                                  float* __restrict__ ad0) {
    int lane = threadIdx.x & 63, wave = threadIdx.x >> 6;
    int rg = wave >> 1, cg = wave & 1;
    int q = lane >> 4, c16 = lane & 15;
    int row0 = blockIdx.x * 32 + rg * 16;
    int arow = row0 + c16;
    if (arow > NN - 1) arow = NN - 1;
    const short* ap = xb + (size_t)arow * NF + q * 8;
    floatx4 acc[5] = {};
#pragma unroll
    for (int ks = 0; ks < 8; ++ks) {
        short8 af = *(const short8*)(ap + ks * 32);
#pragma unroll
        for (int tt = 0; tt < 4; ++tt) {
            int t = cg * 4 + tt;
            short8 bf = *(const short8*)(Bp + (((size_t)t * 8 + ks) * 64 + lane) * 8);
            acc[tt] = __builtin_amdgcn_mfma_f32_16x16x32_bf16(af, bf, acc[tt], 0, 0, 0);
        }
        if (cg) {  // wave-uniform: alpha tile t=8
            short8 bf = *(const short8*)(Bp + (((size_t)8 * 8 + ks) * 64 + lane) * 8);
            acc[4] = __builtin_amdgcn_mfma_f32_16x16x32_bf16(af, bf, acc[4], 0, 0, 0);
        }
    }
#pragma unroll
    for (int r = 0; r < 4; ++r) {
        int grow = row0 + q * 4 + r;
        if (grow >= NN) continue;
#pragma unroll
        for (int tt = 0; tt < 4; ++tt)
            h0b[(size_t)grow * NHID + cg * 64 + tt * 16 + c16] =
                (ushort)f2bf(acc[tt][r]);
        if (cg) {
            float v = acc[4][r];
            if (c16 < 8) as0[grow * 8 + c16] = v;
            else         ad0[grow * 8 + (c16 - 8)] = v;
        }
    }
}

// out = log_softmax( AGG @ Bp1 + b1 )
__global__ __launch_bounds__(256) void gemm1_mfma(const short* __restrict__ AGG,
                                                  const short* __restrict__ Bp,
                                                  const float* __restrict__ b1,
                                                  float* __restrict__ out) {
    int lane = threadIdx.x & 63, wave = threadIdx.x >> 6;
    int q = lane >> 4, c16 = lane & 15;
    int row0 = blockIdx.x * 64 + wave * 16;
    int arow = row0 + c16;
    if (arow > NN - 1) arow = NN - 1;
    const short* ap = AGG + (size_t)arow * 1024 + q * 8;
    floatx4 acc[4] = {};
    for (int ks = 0; ks < 32; ++ks) {
        short8 af = *(const short8*)(ap + ks * 32);
#pragma unroll
        for (int t = 0; t < 4; ++t) {
            short8 bf = *(const short8*)(Bp + (((size_t)t * 32 + ks) * 64 + lane) * 8);
            acc[t] = __builtin_amdgcn_mfma_f32_16x16x32_bf16(af, bf, acc[t], 0, 0, 0);
        }
    }
    float bias[4];
#pragma unroll
    for (int t = 0; t < 4; ++t) bias[t] = b1[t * 16 + c16];
#pragma unroll
    for (int r = 0; r < 4; ++r) {
        int grow = row0 + q * 4 + r;
        float z[4];
        float mx = -INFINITY;
#pragma unroll
        for (int t = 0; t < 4; ++t) {
            z[t] = acc[t][r] + bias[t];
            mx = fmaxf(mx, z[t]);
        }
        mx = fmaxf(mx, __shfl_xor(mx, 1));
        mx = fmaxf(mx, __shfl_xor(mx, 2));
        mx = fmaxf(mx, __shfl_xor(mx, 4));
        mx = fmaxf(mx, __shfl_xor(mx, 8));
        float s = 0.f;
#pragma unroll
        for (int t = 0; t < 4; ++t) s += expf(z[t] - mx);
        s += __shfl_xor(s, 1);
        s += __shfl_xor(s, 2);
        s += __shfl_xor(s, 4);
        s += __shfl_xor(s, 8);
        float lse = mx + logf(s);
        if (grow < NN) {
#pragma unroll
            for (int t = 0; t < 4; ++t)
                out[(size_t)grow * NCLS + t * 16 + c16] = z[t] - lse;
        }
    }
}

// as1[n,h] = x1[n,:] . wS[h,:]   (x1 in bf16, uint4-vectorized)
__global__ void alpha1_kernel(const ushort* __restrict__ x1b, const float* __restrict__ wS,
                              const float* __restrict__ wD, float* __restrict__ as_out,
                              float* __restrict__ ad_out) {
    int idx = blockIdx.x * 256 + threadIdx.x;
    if (idx >= NN * HEADS) return;
    int n = idx >> 3, h = idx & 7;
    const uint4* xp = (const uint4*)(x1b + (size_t)n * NHID);
    const float* sp = wS + h * NHID;
    const float* dp = wD + h * NHID;
    float s = 0.f, d = 0.f;
#pragma unroll
    for (int c = 0; c < 16; ++c) {
        uint4 v = xp[c];
        float f[8] = {bf16lo(v.x), bf16hi(v.x), bf16lo(v.y), bf16hi(v.y),
                      bf16lo(v.z), bf16hi(v.z), bf16lo(v.w), bf16hi(v.w)};
#pragma unroll
        for (int j = 0; j < 8; ++j) {
            s += f[j] * sp[c * 8 + j];
            d += f[j] * dp[c * 8 + j];
        }
    }
    as_out[idx] = s;
    ad_out[idx] = d;
}

// ---------------- fused edge kernels ----------------
// One wave per dst, single pass; softmax without max subtraction (shift-invariant,
// logits O(+-6)). Depth-2 pipelines: (a) next chunk's csr load + as-gather issued at
// chunk top, expf finalized after the gather loop; (b) inside the gather loop, edge
// g2+1's shuffle+load issued before edge g2's FMAs. VGPR stays < 48 (occupancy cliff
// at 64 due to allocation granularity — r6/r7 evidence).

__global__ __launch_bounds__(256) void fused_edge0(
    const int* __restrict__ rs, const int* __restrict__ deg, const int* __restrict__ csr,
    const ushort* __restrict__ h0b, const float* __restrict__ as0, const float* __restrict__ ad0,
    const float* __restrict__ b0, ushort* __restrict__ x1b) {
    int d = (blockIdx.x * 256 + threadIdx.x) >> 6;
    int lane = threadIdx.x & 63;
    if (d >= NN) return;
    int row = rs[d], dg = deg[d];
    int hl = lane & 7, g = lane >> 3;
    int hp = lane >> 3;  // head owning this lane's dim pair
    float adv = ad0[d * 8 + hl];
    float den = 0.f;
    float2 acc = {0.f, 0.f};
    // chunk 0 prologue
    int s = (g < dg) ? csr[row + g] : 0;
    float ev0 = as0[s * 8 + hl] + adv;
    ev0 = ev0 > 0.f ? ev0 : 0.2f * ev0;
    float p = (g < dg) ? __expf(ev0) : 0.f;
    for (int base = 0; base < dg; base += 8) {
        // issue next chunk's csr + as-gather early
        int inext = base + 8 + g;
        int s_next = 0;
        if (base + 8 < dg) s_next = (inext < dg) ? csr[row + inext] : 0;
        float evn = as0[s_next * 8 + hl];
        den += p;
        int nv = dg - base;
        if (nv > 8) nv = 8;
        // depth-2 gather pipeline
        int sg = __shfl(s, 0);
        uint v = *(const uint*)(h0b + (size_t)sg * NHID + 2 * lane);
        for (int g2 = 0; g2 < nv; ++g2) {
            int sgn = __shfl(s, ((g2 + 1) & 7) * 8);
            uint vn = *(const uint*)(h0b + (size_t)sgn * NHID + 2 * lane);
            float ph = __shfl(p, g2 * 8 + hp);
            acc.x += bf16lo(v) * ph;
            acc.y += bf16hi(v) * ph;
            v = vn;
        }
        // finalize next chunk's p
        float ev = evn + adv;
        ev = ev > 0.f ? ev : 0.2f * ev;
        p = (inext < dg) ? __expf(ev) : 0.f;
        s = s_next;
    }
    den += __shfl_xor(den, 8);
    den += __shfl_xor(den, 16);
    den += __shfl_xor(den, 32);
    float dh = __shfl(den, hp);
    float inv = 1.f / (dh + 1e-16f);
    float2 bb = ((const float2*)b0)[lane];
    float o0 = acc.x * inv + bb.x;
    float o1 = acc.y * inv + bb.y;
    o0 = o0 > 0.f ? o0 : expf(o0) - 1.f;
    o1 = o1 > 0.f ? o1 : expf(o1) - 1.f;
    *(uint*)(x1b + (size_t)d * NHID + 2 * lane) = packbf16(o0, o1);
}

__global__ __launch_bounds__(256) void fused_edge1(
    const int* __restrict__ rs, const int* __restrict__ deg, const int* __restrict__ csr,
    const ushort* __restrict__ x1b, const float* __restrict__ as1, const float* __restrict__ ad1,
    ushort* __restrict__ AGG) {
    int d = (blockIdx.x * 256 + threadIdx.x) >> 6;
    int lane = threadIdx.x & 63;
    if (d >= NN) return;
    int row = rs[d], dg = deg[d];
    int hl = lane & 7, g = lane >> 3;
    float adv = ad1[d * 8 + hl];
    float den = 0.f;
    float2 acc[HEADS] = {};
    // chunk 0 prologue
    int s = (g < dg) ? csr[row + g] : 0;
    float ev0 = as1[s * 8 + hl] + adv;
    ev0 = ev0 > 0.f ? ev0 : 0.2f * ev0;
    float p = (g < dg) ? __expf(ev0) : 0.f;
    for (int base = 0; base < dg; base += 8) {
        int inext = base + 8 + g;
        int s_next = 0;
        if (base + 8 < dg) s_next = (inext < dg) ? csr[row + inext] : 0;
        float evn = as1[s_next * 8 + hl];
        den += p;
        int nv = dg - base;
        if (nv > 8) nv = 8;
        int sg = __shfl(s, 0);
        uint v = *(const uint*)(x1b + (size_t)sg * NHID + 2 * lane);
        for (int g2 = 0; g2 < nv; ++g2) {
            int sgn = __shfl(s, ((g2 + 1) & 7) * 8);
            uint vn = *(const uint*)(x1b + (size_t)sgn * NHID + 2 * lane);
            float2 xv = {bf16lo(v), bf16hi(v)};
#pragma unroll
            for (int h = 0; h < HEADS; ++h) {
                float ph = __shfl(p, g2 * 8 + h);
                acc[h].x += xv.x * ph;
                acc[h].y += xv.y * ph;
            }
            v = vn;
        }
        float ev = evn + adv;
        ev = ev > 0.f ? ev : 0.2f * ev;
        p = (inext < dg) ? __expf(ev) : 0.f;
        s = s_next;
    }
    den += __shfl_xor(den, 8);
    den += __shfl_xor(den, 16);
    den += __shfl_xor(den, 32);
#pragma unroll
    for (int h = 0; h < HEADS; ++h) {
        float dh = __shfl(den, h);
        float inv = 1.f / (dh + 1e-16f);
        *(uint*)(AGG + (size_t)d * 1024 + h * NHID + 2 * lane) =
            packbf16(acc[h].x * inv, acc[h].y * inv);
    }
}

// ---------------- launch ----------------

extern "C" void kernel_launch(void* const* d_in, const int* in_sizes, int n_in,
                              void* d_out, int out_size, void* d_ws, size_t ws_size,
                              hipStream_t stream) {
    const float* x   = (const float*)d_in[0];
    const int*   ei  = (const int*)d_in[1];
    const float* W0  = (const float*)d_in[2];
    const float* aS0 = (const float*)d_in[3];
    const float* aD0 = (const float*)d_in[4];
    const float* b0  = (const float*)d_in[5];
    const float* W1  = (const float*)d_in[6];
    const float* aS1 = (const float*)d_in[7];
    const float* aD1 = (const float*)d_in[8];
    const float* b1  = (const float*)d_in[9];
    float* out = (float*)d_out;

    char* ws = (char*)d_ws;
    ushort* x1b = (ushort*)ws; ws += (size_t)NN * NHID * 2;           // 12.8 MB
    ushort* h0b = (ushort*)ws; ws += (size_t)NN * NHID * 2;           // 12.8 MB
    ushort* AGG = (ushort*)ws; ws += (size_t)NN * 1024 * 2;           // 102.4 MB
    short* xb   = (short*)ws; ws += (size_t)NN * NF * 2;              // 25.6 MB
    float* as0  = (float*)ws; ws += (size_t)NN * HEADS * 4;
    float* ad0  = (float*)ws; ws += (size_t)NN * HEADS * 4;
    float* as1  = (float*)ws; ws += (size_t)NN * HEADS * 4;
    float* ad1  = (float*)ws; ws += (size_t)NN * HEADS * 4;
    short* Bp0  = (short*)ws; ws += (size_t)PK0 * 2;
    short* Bp1  = (short*)ws; ws += (size_t)PK1 * 2;
    float* wS   = (float*)ws; ws += (size_t)HEADS * NHID * 4;
    float* wD   = (float*)ws; ws += (size_t)HEADS * NHID * 4;
    int* deg    = (int*)ws; ws += (size_t)NN * 4;
    int* cnt2   = (int*)ws; ws += (size_t)NN * 4;                     // adjacent to deg
    int* rs     = (int*)ws; ws += (size_t)NN * 4;
    int* bsum   = (int*)ws; ws += 256 * 4;
    int* bsumx  = (int*)ws; ws += 256 * 4;
    int* csr    = (int*)ws; ws += (size_t)NE * 4;                     // 2.4 MB

    const int NH = NN * HEADS;
    const int FUSEDN = CASTN + NE + PREPN;

    // ---- zero deg + cnt2, then fused cast/degree/weight-prep ----
    hipMemsetAsync(deg, 0, (size_t)2 * NN * 4, stream);
    fused_prep_kernel<<<(FUSEDN + 255) / 256, 256, 0, stream>>>(
        x, xb, ei, deg, W0, aS0, aD0, W1, aS1, aD1, Bp0, Bp1, wS, wD);

    // ---- CSR scan + scatter ----
    scan1_kernel<<<NB1, 256, 0, stream>>>(deg, rs, bsum);
    scan2_kernel<<<1, 256, 0, stream>>>(bsum, bsumx);
    scan3_kernel<<<NB1, 256, 0, stream>>>(rs, bsumx);
    scatter_kernel<<<(NE + 255) / 256, 256, 0, stream>>>(ei, rs, cnt2, csr);

    // ---- layer 0 ----
    gemm0_mfma<<<(NN + 31) / 32, 256, 0, stream>>>(xb, Bp0, h0b, as0, ad0);
    fused_edge0<<<(NN + 3) / 4, 256, 0, stream>>>(rs, deg, csr, h0b, as0, ad0, b0, x1b);

    // ---- layer 1 ----
    alpha1_kernel<<<(NH + 255) / 256, 256, 0, stream>>>(x1b, wS, wD, as1, ad1);
    fused_edge1<<<(NN + 3) / 4, 256, 0, stream>>>(rs, deg, csr, x1b, as1, ad1, AGG);
    gemm1_mfma<<<(NN + 63) / 64, 256, 0, stream>>>((const short*)AGG, Bp1, b1, out);
}

// Round 10
// 377.546 us; speedup vs baseline: 1.1129x; 1.0722x over previous
//
#include <hip/hip_runtime.h>
#include <hip/hip_bf16.h>
#include <math.h>

#define NN 50000
#define NE 600000
#define NF 256
#define NHID 128
#define HEADS 8
#define D0 16
#define NCLS 64
#define NB1 196  // (NN+255)/256

#define PK0 (9 * 8 * 64 * 8)   // Bp0: 8 col-tiles of W0 + 1 alpha tile (W0A)
#define PK1 (4 * 32 * 64 * 8)  // Bp1
#define PKA (4 * 64 * 8)       // wA1b: K=128, N=16 (cols 0-7 wS heads, 8-15 wD)
#define CASTN (NN * NF / 4)    // 3.2M float4 groups
#define PREPN (PK0 + PK1 + PKA)

typedef __attribute__((ext_vector_type(8))) short short8;
typedef __attribute__((ext_vector_type(4))) float floatx4;

__device__ __forceinline__ float bf16lo(uint v) { return __uint_as_float((v & 0xffffu) << 16); }
__device__ __forceinline__ float bf16hi(uint v) { return __uint_as_float(v & 0xffff0000u); }
__device__ __forceinline__ uint packbf16(float a, float b) {
    return (uint)__bfloat16_as_ushort(__float2bfloat16(a)) |
           ((uint)__bfloat16_as_ushort(__float2bfloat16(b)) << 16);
}
__device__ __forceinline__ short f2bf(float v) {
    return (short)__bfloat16_as_ushort(__float2bfloat16(v));
}

// ---------------- CSR scan/scatter ----------------

__global__ void scan1_kernel(const int* __restrict__ deg, int* __restrict__ rs,
                             int* __restrict__ bsum) {
    __shared__ int sh[256];
    int tid = threadIdx.x;
    int i = blockIdx.x * 256 + tid;
    int v = (i < NN) ? deg[i] : 0;
    sh[tid] = v;
    __syncthreads();
    for (int off = 1; off < 256; off <<= 1) {
        int t = (tid >= off) ? sh[tid - off] : 0;
        __syncthreads();
        sh[tid] += t;
        __syncthreads();
    }
    if (i < NN) rs[i] = sh[tid] - v;  // exclusive
    if (tid == 255) bsum[blockIdx.x] = sh[255];
}

__global__ void scan2_kernel(const int* __restrict__ bsum, int* __restrict__ bsumx) {
    __shared__ int sh[256];
    int tid = threadIdx.x;
    int v = (tid < NB1) ? bsum[tid] : 0;
    sh[tid] = v;
    __syncthreads();
    for (int off = 1; off < 256; off <<= 1) {
        int t = (tid >= off) ? sh[tid - off] : 0;
        __syncthreads();
        sh[tid] += t;
        __syncthreads();
    }
    if (tid < NB1) bsumx[tid] = sh[tid] - v;
}

__global__ void scan3_kernel(int* __restrict__ rs, const int* __restrict__ bsumx) {
    int i = blockIdx.x * 256 + threadIdx.x;
    if (i < NN) rs[i] += bsumx[i >> 8];
}

__global__ void scatter_kernel(const int* __restrict__ ei, const int* __restrict__ rs,
                               int* __restrict__ cnt2, int* __restrict__ csr) {
    int e = blockIdx.x * 256 + threadIdx.x;
    if (e >= NE) return;
    int s = ei[e], d = ei[NE + e];
    int pos = rs[d] + atomicAdd(&cnt2[d], 1);
    csr[pos] = s;
}

// ---------------- fused cast + degree + weight-prep (independent streams) ----------------

__global__ void fused_prep_kernel(const float* __restrict__ x, short* __restrict__ xb,
                                  const int* __restrict__ ei, int* __restrict__ deg,
                                  const float* __restrict__ W0, const float* __restrict__ aS0,
                                  const float* __restrict__ aD0, const float* __restrict__ W1,
                                  const float* __restrict__ aS1, const float* __restrict__ aD1,
                                  short* __restrict__ Bp0, short* __restrict__ Bp1,
                                  short* __restrict__ wA1b) {
    int i = blockIdx.x * 256 + threadIdx.x;
    if (i < CASTN) {
        float4 v = ((const float4*)x)[i];
        short4 r;
        r.x = f2bf(v.x); r.y = f2bf(v.y); r.z = f2bf(v.z); r.w = f2bf(v.w);
        ((short4*)xb)[i] = r;
        return;
    }
    int e = i - CASTN;
    if (e < NE) {
        atomicAdd(&deg[ei[NE + e]], 1);
        return;
    }
    int tid = e - NE;
    if (tid < PK0) {
        int j = tid & 7, l = (tid >> 3) & 63, ks = (tid >> 9) & 7, t = tid >> 12;
        int k = ks * 32 + (l >> 4) * 8 + j;
        float v;
        if (t < 8) {
            int c = t * 16 + (l & 15);
            v = W0[(size_t)k * 128 + c];
        } else {  // alpha tile: col jj<8 -> as0 head jj; jj>=8 -> ad0 head jj-8
            int jj = l & 15;
            int hh = jj & 7;
            const float* av = (jj < 8) ? aS0 : aD0;
            float sum = 0.f;
            for (int dd = 0; dd < D0; ++dd)
                sum += W0[(size_t)k * 128 + hh * D0 + dd] * av[hh * D0 + dd];
            v = sum;
        }
        Bp0[tid] = f2bf(v);
    } else if (tid < PK0 + PK1) {
        int t2 = tid - PK0;
        int j = t2 & 7, l = (t2 >> 3) & 63, ks = (t2 >> 9) & 31, t = t2 >> 14;
        int kk = ks * 32 + (l >> 4) * 8 + j;
        int c = t * 16 + (l & 15);
        Bp1[t2] = f2bf(W1[(size_t)(kk & 127) * 512 + (kk >> 7) * 64 + c] * 0.125f);
    } else if (tid < PREPN) {
        // wA1b packed MFMA B-frag: K=128 (x1 dims), N=16: cols 0-7 = wS head c,
        // cols 8-15 = wD head c-8; w[h,k] = sum_d W1[k, h*64+d] * a1[h,d]
        int t3 = tid - PK0 - PK1;
        int j = t3 & 7, l = (t3 >> 3) & 63, ks = t3 >> 9;  // ks 0..3
        int k = ks * 32 + (l >> 4) * 8 + j;
        int c = l & 15;
        int h = c & 7;
        const float* av = (c < 8) ? aS1 : aD1;
        float sum = 0.f;
        for (int d2 = 0; d2 < NCLS; ++d2)
            sum += W1[(size_t)k * 512 + h * NCLS + d2] * av[h * NCLS + d2];
        wA1b[t3] = f2bf(sum);
    }
}

// ---------------- MFMA GEMMs ----------------

// h0b = xb @ W0 (bf16 out) AND as0/ad0 = xb @ W0A (alpha tile), fused.
__global__ __launch_bounds__(256) void gemm0_mfma(const short* __restrict__ xb,
                                                  const short* __restrict__ Bp,
                                                  ushort* __restrict__ h0b,
                                                  float* __restrict__ as0,
                                                  float* __restrict__ ad0) {
    int lane = threadIdx.x & 63, wave = threadIdx.x >> 6;
    int rg = wave >> 1, cg = wave & 1;
    int q = lane >> 4, c16 = lane & 15;
    int row0 = blockIdx.x * 32 + rg * 16;
    int arow = row0 + c16;
    if (arow > NN - 1) arow = NN - 1;
    const short* ap = xb + (size_t)arow * NF + q * 8;
    floatx4 acc[5] = {};
#pragma unroll
    for (int ks = 0; ks < 8; ++ks) {
        short8 af = *(const short8*)(ap + ks * 32);
#pragma unroll
        for (int tt = 0; tt < 4; ++tt) {
            int t = cg * 4 + tt;
            short8 bf = *(const short8*)(Bp + (((size_t)t * 8 + ks) * 64 + lane) * 8);
            acc[tt] = __builtin_amdgcn_mfma_f32_16x16x32_bf16(af, bf, acc[tt], 0, 0, 0);
        }
        if (cg) {  // wave-uniform: alpha tile t=8
            short8 bf = *(const short8*)(Bp + (((size_t)8 * 8 + ks) * 64 + lane) * 8);
            acc[4] = __builtin_amdgcn_mfma_f32_16x16x32_bf16(af, bf, acc[4], 0, 0, 0);
        }
    }
#pragma unroll
    for (int r = 0; r < 4; ++r) {
        int grow = row0 + q * 4 + r;
        if (grow >= NN) continue;
#pragma unroll
        for (int tt = 0; tt < 4; ++tt)
            h0b[(size_t)grow * NHID + cg * 64 + tt * 16 + c16] =
                (ushort)f2bf(acc[tt][r]);
        if (cg) {
            float v = acc[4][r];
            if (c16 < 8) as0[grow * 8 + c16] = v;
            else         ad0[grow * 8 + (c16 - 8)] = v;
        }
    }
}

// as1/ad1 = x1b @ wA1b  (tiny MFMA: 16 rows/wave, K=128, N=16)
__global__ __launch_bounds__(256) void alpha1_mfma(const ushort* __restrict__ x1b,
                                                   const short* __restrict__ wA1b,
                                                   float* __restrict__ as1,
                                                   float* __restrict__ ad1) {
    int lane = threadIdx.x & 63, wave = threadIdx.x >> 6;
    int q = lane >> 4, c16 = lane & 15;
    int row0 = blockIdx.x * 64 + wave * 16;
    int arow = row0 + c16;
    if (arow > NN - 1) arow = NN - 1;
    const short* ap = (const short*)x1b + (size_t)arow * NHID + q * 8;
    floatx4 acc = {};
#pragma unroll
    for (int ks = 0; ks < 4; ++ks) {
        short8 af = *(const short8*)(ap + ks * 32);
        short8 bf = *(const short8*)(wA1b + (((size_t)ks) * 64 + lane) * 8);
        acc = __builtin_amdgcn_mfma_f32_16x16x32_bf16(af, bf, acc, 0, 0, 0);
    }
#pragma unroll
    for (int r = 0; r < 4; ++r) {
        int grow = row0 + q * 4 + r;
        if (grow >= NN) continue;
        float v = acc[r];
        if (c16 < 8) as1[grow * 8 + c16] = v;
        else         ad1[grow * 8 + (c16 - 8)] = v;
    }
}

// out = log_softmax( AGG @ Bp1 + b1 )
__global__ __launch_bounds__(256) void gemm1_mfma(const short* __restrict__ AGG,
                                                  const short* __restrict__ Bp,
                                                  const float* __restrict__ b1,
                                                  float* __restrict__ out) {
    int lane = threadIdx.x & 63, wave = threadIdx.x >> 6;
    int q = lane >> 4, c16 = lane & 15;
    int row0 = blockIdx.x * 64 + wave * 16;
    int arow = row0 + c16;
    if (arow > NN - 1) arow = NN - 1;
    const short* ap = AGG + (size_t)arow * 1024 + q * 8;
    floatx4 acc[4] = {};
    for (int ks = 0; ks < 32; ++ks) {
        short8 af = *(const short8*)(ap + ks * 32);
#pragma unroll
        for (int t = 0; t < 4; ++t) {
            short8 bf = *(const short8*)(Bp + (((size_t)t * 32 + ks) * 64 + lane) * 8);
            acc[t] = __builtin_amdgcn_mfma_f32_16x16x32_bf16(af, bf, acc[t], 0, 0, 0);
        }
    }
    float bias[4];
#pragma unroll
    for (int t = 0; t < 4; ++t) bias[t] = b1[t * 16 + c16];
#pragma unroll
    for (int r = 0; r < 4; ++r) {
        int grow = row0 + q * 4 + r;
        float z[4];
        float mx = -INFINITY;
#pragma unroll
        for (int t = 0; t < 4; ++t) {
            z[t] = acc[t][r] + bias[t];
            mx = fmaxf(mx, z[t]);
        }
        mx = fmaxf(mx, __shfl_xor(mx, 1));
        mx = fmaxf(mx, __shfl_xor(mx, 2));
        mx = fmaxf(mx, __shfl_xor(mx, 4));
        mx = fmaxf(mx, __shfl_xor(mx, 8));
        float s = 0.f;
#pragma unroll
        for (int t = 0; t < 4; ++t) s += expf(z[t] - mx);
        s += __shfl_xor(s, 1);
        s += __shfl_xor(s, 2);
        s += __shfl_xor(s, 4);
        s += __shfl_xor(s, 8);
        float lse = mx + logf(s);
        if (grow < NN) {
#pragma unroll
            for (int t = 0; t < 4; ++t)
                out[(size_t)grow * NCLS + t * 16 + c16] = z[t] - lse;
        }
    }
}

// ---------------- fused edge kernels ----------------
// softmax without max subtraction (shift-invariant; logits O(+-6)).

// Layer 0: one wave per dst (r9 pipelined form — VGPR 32, proven).
__global__ __launch_bounds__(256) void fused_edge0(
    const int* __restrict__ rs, const int* __restrict__ deg, const int* __restrict__ csr,
    const ushort* __restrict__ h0b, const float* __restrict__ as0, const float* __restrict__ ad0,
    const float* __restrict__ b0, ushort* __restrict__ x1b) {
    int d = (blockIdx.x * 256 + threadIdx.x) >> 6;
    int lane = threadIdx.x & 63;
    if (d >= NN) return;
    int row = rs[d], dg = deg[d];
    int hl = lane & 7, g = lane >> 3;
    int hp = lane >> 3;  // head owning this lane's dim pair
    float adv = ad0[d * 8 + hl];
    float den = 0.f;
    float2 acc = {0.f, 0.f};
    int s = (g < dg) ? csr[row + g] : 0;
    float ev0 = as0[s * 8 + hl] + adv;
    ev0 = ev0 > 0.f ? ev0 : 0.2f * ev0;
    float p = (g < dg) ? __expf(ev0) : 0.f;
    for (int base = 0; base < dg; base += 8) {
        int inext = base + 8 + g;
        int s_next = 0;
        if (base + 8 < dg) s_next = (inext < dg) ? csr[row + inext] : 0;
        float evn = as0[s_next * 8 + hl];
        den += p;
        int nv = dg - base;
        if (nv > 8) nv = 8;
        int sg = __shfl(s, 0);
        uint v = *(const uint*)(h0b + (size_t)sg * NHID + 2 * lane);
        for (int g2 = 0; g2 < nv; ++g2) {
            int sgn = __shfl(s, ((g2 + 1) & 7) * 8);
            uint vn = *(const uint*)(h0b + (size_t)sgn * NHID + 2 * lane);
            float ph = __shfl(p, g2 * 8 + hp);
            acc.x += bf16lo(v) * ph;
            acc.y += bf16hi(v) * ph;
            v = vn;
        }
        float ev = evn + adv;
        ev = ev > 0.f ? ev : 0.2f * ev;
        p = (inext < dg) ? __expf(ev) : 0.f;
        s = s_next;
    }
    den += __shfl_xor(den, 8);
    den += __shfl_xor(den, 16);
    den += __shfl_xor(den, 32);
    float dh = __shfl(den, hp);
    float inv = 1.f / (dh + 1e-16f);
    float2 bb = ((const float2*)b0)[lane];
    float o0 = acc.x * inv + bb.x;
    float o1 = acc.y * inv + bb.y;
    o0 = o0 > 0.f ? o0 : expf(o0) - 1.f;
    o1 = o1 > 0.f ? o1 : expf(o1) - 1.f;
    *(uint*)(x1b + (size_t)d * NHID + 2 * lane) = packbf16(o0, o1);
}

// Layer 1: TWO waves per dst (head-split: wave w handles heads w*4..w*4+3).
// 16-edge chunks (lane: eslot=lane>>2, hh=lane&3). Halves per-edge FMA+shuffle,
// halves acc regs, doubles TLP. Both waves of a dst share a block -> second
// gather of each row hits L1/L2.
__global__ __launch_bounds__(256) void fused_edge1(
    const int* __restrict__ rs, const int* __restrict__ deg, const int* __restrict__ csr,
    const ushort* __restrict__ x1b, const float* __restrict__ as1, const float* __restrict__ ad1,
    ushort* __restrict__ AGG) {
    int gw = (blockIdx.x * 256 + threadIdx.x) >> 6;
    int d = gw >> 1;
    int w = gw & 1;
    int lane = threadIdx.x & 63;
    if (d >= NN) return;
    int row = rs[d], dg = deg[d];
    int hh = lane & 3, eslot = lane >> 2;
    float adv = ad1[d * 8 + w * 4 + hh];
    float den = 0.f;
    float2 acc[4] = {};
    for (int base = 0; base < dg; base += 16) {
        int i = base + eslot;
        int s = (i < dg) ? csr[row + i] : 0;
        float ev = as1[s * 8 + w * 4 + hh] + adv;
        ev = ev > 0.f ? ev : 0.2f * ev;
        float p = (i < dg) ? __expf(ev) : 0.f;
        den += p;
        int nv = dg - base;
        if (nv > 16) nv = 16;
        for (int g2 = 0; g2 < nv; ++g2) {
            int sg = __shfl(s, g2 * 4);
            uint v = *(const uint*)(x1b + (size_t)sg * NHID + 2 * lane);
            float2 xv = {bf16lo(v), bf16hi(v)};
#pragma unroll
            for (int h = 0; h < 4; ++h) {
                float ph = __shfl(p, g2 * 4 + h);
                acc[h].x += xv.x * ph;
                acc[h].y += xv.y * ph;
            }
        }
    }
    den += __shfl_xor(den, 4);
    den += __shfl_xor(den, 8);
    den += __shfl_xor(den, 16);
    den += __shfl_xor(den, 32);
#pragma unroll
    for (int h = 0; h < 4; ++h) {
        float dh = __shfl(den, h);  // lane h holds den for head class h
        float inv = 1.f / (dh + 1e-16f);
        *(uint*)(AGG + (size_t)d * 1024 + (w * 4 + h) * NHID + 2 * lane) =
            packbf16(acc[h].x * inv, acc[h].y * inv);
    }
}

// ---------------- launch ----------------

extern "C" void kernel_launch(void* const* d_in, const int* in_sizes, int n_in,
                              void* d_out, int out_size, void* d_ws, size_t ws_size,
                              hipStream_t stream) {
    const float* x   = (const float*)d_in[0];
    const int*   ei  = (const int*)d_in[1];
    const float* W0  = (const float*)d_in[2];
    const float* aS0 = (const float*)d_in[3];
    const float* aD0 = (const float*)d_in[4];
    const float* b0  = (const float*)d_in[5];
    const float* W1  = (const float*)d_in[6];
    const float* aS1 = (const float*)d_in[7];
    const float* aD1 = (const float*)d_in[8];
    const float* b1  = (const float*)d_in[9];
    float* out = (float*)d_out;

    char* ws = (char*)d_ws;
    ushort* x1b = (ushort*)ws; ws += (size_t)NN * NHID * 2;           // 12.8 MB
    ushort* h0b = (ushort*)ws; ws += (size_t)NN * NHID * 2;           // 12.8 MB
    ushort* AGG = (ushort*)ws; ws += (size_t)NN * 1024 * 2;           // 102.4 MB
    short* xb   = (short*)ws; ws += (size_t)NN * NF * 2;              // 25.6 MB
    float* as0  = (float*)ws; ws += (size_t)NN * HEADS * 4;
    float* ad0  = (float*)ws; ws += (size_t)NN * HEADS * 4;
    float* as1  = (float*)ws; ws += (size_t)NN * HEADS * 4;
    float* ad1  = (float*)ws; ws += (size_t)NN * HEADS * 4;
    short* Bp0  = (short*)ws; ws += (size_t)PK0 * 2;
    short* Bp1  = (short*)ws; ws += (size_t)PK1 * 2;
    short* wA1b = (short*)ws; ws += (size_t)PKA * 2;
    int* deg    = (int*)ws; ws += (size_t)NN * 4;
    int* cnt2   = (int*)ws; ws += (size_t)NN * 4;                     // adjacent to deg
    int* rs     = (int*)ws; ws += (size_t)NN * 4;
    int* bsum   = (int*)ws; ws += 256 * 4;
    int* bsumx  = (int*)ws; ws += 256 * 4;
    int* csr    = (int*)ws; ws += (size_t)NE * 4;                     // 2.4 MB

    const int FUSEDN = CASTN + NE + PREPN;

    // ---- zero deg + cnt2, then fused cast/degree/weight-prep ----
    hipMemsetAsync(deg, 0, (size_t)2 * NN * 4, stream);
    fused_prep_kernel<<<(FUSEDN + 255) / 256, 256, 0, stream>>>(
        x, xb, ei, deg, W0, aS0, aD0, W1, aS1, aD1, Bp0, Bp1, wA1b);

    // ---- CSR scan + scatter ----
    scan1_kernel<<<NB1, 256, 0, stream>>>(deg, rs, bsum);
    scan2_kernel<<<1, 256, 0, stream>>>(bsum, bsumx);
    scan3_kernel<<<NB1, 256, 0, stream>>>(rs, bsumx);
    scatter_kernel<<<(NE + 255) / 256, 256, 0, stream>>>(ei, rs, cnt2, csr);

    // ---- layer 0 ----
    gemm0_mfma<<<(NN + 31) / 32, 256, 0, stream>>>(xb, Bp0, h0b, as0, ad0);
    fused_edge0<<<(NN + 3) / 4, 256, 0, stream>>>(rs, deg, csr, h0b, as0, ad0, b0, x1b);

    // ---- layer 1 ----
    alpha1_mfma<<<(NN + 63) / 64, 256, 0, stream>>>(x1b, wA1b, as1, ad1);
    fused_edge1<<<(2 * NN + 3) / 4, 256, 0, stream>>>(rs, deg, csr, x1b, as1, ad1, AGG);
    gemm1_mfma<<<(NN + 63) / 64, 256, 0, stream>>>((const short*)AGG, Bp1, b1, out);
}